// Round 7
// baseline (183.616 us; speedup 1.0000x reference)
//
#include <hip/hip_runtime.h>
#include <math.h>

#define HW    409600      // 640*640
#define HW4   102400      // float4-quads per (batch,dim)
#define BATCH 8
#define NLAB  33
#define GXB   200         // blocks per batch; 2 quads/thread -> 1600 blocks
#define NREP  8           // LDS sum-bin replicas (per 8-lane cluster)
#define RS4   137         // replica stride (33*4=132 fields + pad; 137%32=9)
// ws float-offset layout:
#define MEANS_OFF 0                        // [8][168]: mean[132], invci@132..164
#define P2_OFF    2048                     // [8][256] pass2 val partials
#define AWS_OFF   4096                     // [8][208] atomic-fallback record
#define P1_OFF    8192                     // [8][200 fields][GXB] transposed partials
#define LABS_OFF_F (P1_OFF + BATCH*200*GXB)          // 328192
#define NEED_SPLIT ((size_t)LABS_OFF_F * 4)
#define NEED_LABS  ((size_t)LABS_OFF_F * 4 + (size_t)BATCH * HW4 * 4)

#if defined(__has_builtin) && __has_builtin(__builtin_amdgcn_sched_barrier)
#define SCHED_PIN() __builtin_amdgcn_sched_barrier(0)
#else
#define SCHED_PIN()
#endif

__global__ void init_aws(float* ws) {   // only for atomic-fallback mode
    int i = blockIdx.x * 256 + threadIdx.x;
    if (i < BATCH * 208) ws[AWS_OFF + i] = 0.f;
}

__device__ __forceinline__ float getc(const float4& v, int e) {
    return (e == 0) ? v.x : (e == 1) ? v.y : (e == 2) ? v.z : v.w;
}
__device__ __forceinline__ float wave_sum(float v) {
    #pragma unroll
    for (int o = 32; o > 0; o >>= 1) v += __shfl_xor(v, o);
    return v;
}

// ---------------- pass1 ----------------
struct Quad { int4 iv; float4 tv, kv, x0, x1, x2, x3; };

__device__ __forceinline__ void loadQ(Quad& q, const int4* inst4, const float4* tm4,
                                      const float4* kern4, const float4* emb4, int g) {
    q.iv = inst4[g];
    q.tv = tm4[g];
    q.kv = kern4[g];
    q.x0 = emb4[g];
    q.x1 = emb4[g + HW4];
    q.x2 = emb4[g + 2 * HW4];
    q.x3 = emb4[g + 3 * HW4];
}

// counts via wave ballots (no LDS atomics); sums via LDS atomics (4 fields, k-masked)
__device__ __forceinline__ void procQ(const Quad& q, float* mb, unsigned* cc,
                                      unsigned* labs, size_t idx) {
    int l0 = (q.tv.x > 0.5f) ? q.iv.x : 0;
    int l1 = (q.tv.y > 0.5f) ? q.iv.y : 0;
    int l2 = (q.tv.z > 0.5f) ? q.iv.z : 0;
    int l3 = (q.tv.w > 0.5f) ? q.iv.w : 0;
    if (labs)
        labs[idx] = (unsigned)l0 | ((unsigned)l1 << 8) |
                    ((unsigned)l2 << 16) | ((unsigned)l3 << 24);

    bool k0 = q.kv.x > 0.5f, k1 = q.kv.y > 0.5f;
    bool k2 = q.kv.z > 0.5f, k3 = q.kv.w > 0.5f;
    // wave-convergent point: ballots (straight-line code, full exec mask)
    unsigned long long km0 = __ballot(k0), km1 = __ballot(k1);
    unsigned long long km2 = __ballot(k2), km3 = __ballot(k3);
    #pragma unroll
    for (int l = 1; l < NLAB; ++l) {
        unsigned long long m0 = __ballot(l0 == l);
        unsigned long long m1 = __ballot(l1 == l);
        unsigned long long m2 = __ballot(l2 == l);
        unsigned long long m3 = __ballot(l3 == l);
        unsigned ci = (unsigned)(__popcll(m0) + __popcll(m1) +
                                 __popcll(m2) + __popcll(m3));
        unsigned ck = (unsigned)(__popcll(m0 & km0) + __popcll(m1 & km1) +
                                 __popcll(m2 & km2) + __popcll(m3 & km3));
        cc[l - 1] += ci + (ck << 16);
    }
    if (l0 && k0) { float* bb = mb + l0 * 4;
        atomicAdd(bb, q.x0.x); atomicAdd(bb+1, q.x1.x);
        atomicAdd(bb+2, q.x2.x); atomicAdd(bb+3, q.x3.x); }
    if (l1 && k1) { float* bb = mb + l1 * 4;
        atomicAdd(bb, q.x0.y); atomicAdd(bb+1, q.x1.y);
        atomicAdd(bb+2, q.x2.y); atomicAdd(bb+3, q.x3.y); }
    if (l2 && k2) { float* bb = mb + l2 * 4;
        atomicAdd(bb, q.x0.z); atomicAdd(bb+1, q.x1.z);
        atomicAdd(bb+2, q.x2.z); atomicAdd(bb+3, q.x3.z); }
    if (l3 && k3) { float* bb = mb + l3 * 4;
        atomicAdd(bb, q.x0.w); atomicAdd(bb+1, q.x1.w);
        atomicAdd(bb+2, q.x2.w); atomicAdd(bb+3, q.x3.w); }
}

template<bool SPLIT>
__global__ __launch_bounds__(256, 6) void pass1(const float* __restrict__ emb,
                                                const int*   __restrict__ inst,
                                                const float* __restrict__ kern,
                                                const float* __restrict__ tmask,
                                                float*       __restrict__ ws,
                                                unsigned*    __restrict__ labs) {
    __shared__ float    bins[NREP][RS4];
    __shared__ unsigned cnts[NLAB];         // packed ci | ck<<16 across 4 waves
    const int t = threadIdx.x, bx = blockIdx.x, b = blockIdx.y;
    const unsigned lane = t & 63;
    float* mb = bins[(t >> 3) & (NREP - 1)];

    const size_t  base  = (size_t)b * HW;
    const float4* emb4  = (const float4*)(emb + base * 4);
    const int4*   inst4 = (const int4*)(inst + base);
    const float4* kern4 = (const float4*)(kern + base);
    const float4* tm4   = (const float4*)(tmask + base);
    const int q0 = bx * 512 + t;
    const size_t lb = (size_t)b * HW4;

    for (int i = t; i < NREP * RS4; i += 256) (&bins[0][0])[i] = 0.f;
    if (t < NLAB) cnts[t] = 0u;
    __syncthreads();

    unsigned cc[NLAB - 1];
    #pragma unroll
    for (int l = 0; l < NLAB - 1; ++l) cc[l] = 0u;

    Quad q;
    loadQ(q, inst4, tm4, kern4, emb4, q0);
    SCHED_PIN();
    procQ(q, mb, cc, labs, lb + q0);
    loadQ(q, inst4, tm4, kern4, emb4, q0 + 256);
    SCHED_PIN();
    procQ(q, mb, cc, labs, lb + q0 + 256);

    // flush per-wave packed counts: lane l holds cc[l-1]
    unsigned vc = 0;
    #pragma unroll
    for (int l = 1; l < NLAB; ++l) vc = (lane == (unsigned)l) ? cc[l - 1] : vc;
    if (lane >= 1 && lane < NLAB) atomicAdd(&cnts[lane], vc);
    __syncthreads();

    // epilogue: record[0..131]=sums, [132+l]=cnt_i, [165+l]=cnt_k
    float v = 0.f;
    if (t < 132) {
        #pragma unroll
        for (int r = 0; r < NREP; ++r) v += bins[r][t];
    } else if (t < 165) {
        v = (float)(cnts[t - 132] & 0xFFFFu);
    } else if (t < 198) {
        v = (float)(cnts[t - 165] >> 16);
    }
    if (t < 198) {
        if (SPLIT)
            ws[P1_OFF + ((size_t)b * 200 + t) * GXB + bx] = v;   // transposed, plain
        else if (v != 0.f)
            atomicAdd(ws + AWS_OFF + b * 208 + t, v);
    }
}

// ---------------- reduce: partials -> means/invci ----------------
template<bool SPLIT>
__global__ __launch_bounds__(256) void reduce_means(float* __restrict__ ws) {
    __shared__ float raw[200];
    const int t = threadIdx.x, b = blockIdx.x;
    const int w = t >> 6, lane = t & 63;
    if (SPLIT) {
        for (int f = w; f < 198; f += 4) {
            const float* p = ws + P1_OFF + ((size_t)b * 200 + f) * GXB;
            float s = 0.f;
            #pragma unroll
            for (int base = 0; base < GXB; base += 64) {
                int i = base + lane;
                if (i < GXB) s += p[i];
            }
            s = wave_sum(s);
            if (lane == 0) raw[f] = s;
        }
    } else {
        if (t < 198) raw[t] = ws[AWS_OFF + b * 208 + t];
    }
    __syncthreads();
    float* mm = ws + MEANS_OFF + b * 168;
    if (t < NLAB) {
        float ci = raw[132 + t], ck = raw[165 + t];
        float inv = 1.f / fmaxf(ck, 1.f);
        float z = (t == 0) ? 0.f : 1.f;
        mm[t * 4 + 0] = z * raw[t * 4 + 0] * inv;
        mm[t * 4 + 1] = z * raw[t * 4 + 1] * inv;
        mm[t * 4 + 2] = z * raw[t * 4 + 2] * inv;
        mm[t * 4 + 3] = z * raw[t * 4 + 3] * inv;
        mm[132 + t]   = 1.f / fmaxf(ci, 1.f);
    }
}

// ---------------- pass2 ----------------
struct Quad2 { unsigned pk; int4 iv; float4 tv, x0, x1, x2, x3; };

template<bool USE_LABS>
__device__ __forceinline__ void loadQ2(Quad2& q, const unsigned* labs, size_t lb,
                                       const int4* inst4, const float4* tm4,
                                       const float4* emb4, int g) {
    if (USE_LABS) {
        q.pk = labs[lb + g];
    } else {
        q.iv = inst4[g];
        q.tv = tm4[g];
    }
    q.x0 = emb4[g];
    q.x1 = emb4[g + HW4];
    q.x2 = emb4[g + 2 * HW4];
    q.x3 = emb4[g + 3 * HW4];
}

template<bool USE_LABS>
__device__ __forceinline__ float procQ2(const Quad2& q, const float4* means4,
                                        const float* invci) {
    unsigned pk;
    if (USE_LABS) {
        pk = q.pk;
    } else {
        pk = (unsigned)((q.tv.x > 0.5f) ? q.iv.x : 0)        |
             ((unsigned)((q.tv.y > 0.5f) ? q.iv.y : 0) << 8) |
             ((unsigned)((q.tv.z > 0.5f) ? q.iv.z : 0) << 16)|
             ((unsigned)((q.tv.w > 0.5f) ? q.iv.w : 0) << 24);
    }
    float acc = 0.f;
    #pragma unroll
    for (int e = 0; e < 4; ++e) {
        int l = (pk >> (8 * e)) & 255;
        if (l) {
            float4 m = means4[l];
            float d0 = getc(q.x0, e) - m.x, d1 = getc(q.x1, e) - m.y;
            float d2 = getc(q.x2, e) - m.z, d3 = getc(q.x3, e) - m.w;
            float dist = sqrtf(d0 * d0 + d1 * d1 + d2 * d2 + d3 * d3);
            float u = fmaxf(dist - 0.5f, 0.f);
            acc += __logf(u * u + 1.f) * invci[l];
        }
    }
    return acc;
}

template<bool USE_LABS>
__global__ __launch_bounds__(256, 8) void pass2(const float* __restrict__ emb,
                                                const int*   __restrict__ inst,
                                                const float* __restrict__ tmask,
                                                float*       __restrict__ ws,
                                                const unsigned* __restrict__ labs) {
    __shared__ float4 means4[NLAB];
    __shared__ float  invci[NLAB];
    __shared__ float  red[4];
    const int t = threadIdx.x, bx = blockIdx.x, b = blockIdx.y;

    const size_t  base  = (size_t)b * HW;
    const float4* emb4  = (const float4*)(emb + base * 4);
    const int4*   inst4 = (const int4*)(inst + base);
    const float4* tm4   = (const float4*)(tmask + base);
    const int q0 = bx * 512 + t;
    const size_t lb = (size_t)b * HW4;

    Quad2 q;
    loadQ2<USE_LABS>(q, labs, lb, inst4, tm4, emb4, q0);
    SCHED_PIN();

    const float* mm = ws + MEANS_OFF + b * 168;
    if (t < NLAB) {
        means4[t] = ((const float4*)mm)[t];
        invci[t]  = mm[132 + t];
    }
    __syncthreads();

    float acc = procQ2<USE_LABS>(q, means4, invci);
    loadQ2<USE_LABS>(q, labs, lb, inst4, tm4, emb4, q0 + 256);
    SCHED_PIN();
    acc += procQ2<USE_LABS>(q, means4, invci);

    acc = wave_sum(acc);
    if ((t & 63) == 0) red[t >> 6] = acc;
    __syncthreads();
    if (t == 0)
        ws[P2_OFF + b * 256 + bx] = red[0] + red[1] + red[2] + red[3];  // plain store
}

// ---------------- final ----------------
__global__ __launch_bounds__(256) void final_kernel(const float* __restrict__ ws,
                                                    float* __restrict__ out) {
    __shared__ float4 means4[NLAB];
    __shared__ float  red[4];
    const int t = threadIdx.x;
    float total = 0.f;
    for (int b = 0; b < BATCH; ++b) {
        __syncthreads();
        const float* mm = ws + MEANS_OFF + b * 168;
        if (t < NLAB) means4[t] = ((const float4*)mm)[t];
        __syncthreads();

        float part = (t < GXB) ? ws[P2_OFF + b * 256 + t] * (1.f / 32.f) : 0.f; // l_agg
        float disp = 0.f;
        for (int p = t; p < 1024; p += 256) {
            int i = p >> 5, j = p & 31;
            if (i != j) {
                float4 mi = means4[i + 1], mj = means4[j + 1];
                float d0 = mi.x - mj.x, d1 = mi.y - mj.y;
                float d2 = mi.z - mj.z, d3 = mi.w - mj.w;
                float pd = sqrtf(d0 * d0 + d1 * d1 + d2 * d2 + d3 * d3);
                float u = fmaxf(3.0f - pd, 0.f);
                disp += __logf(u * u + 1.f);
            }
        }
        disp *= 1.f / 992.f;                                  // 32*31
        float regp = 0.f;
        if (t >= 1 && t < NLAB) {
            float4 m = means4[t];
            float n2 = m.x * m.x + m.y * m.y + m.z * m.z + m.w * m.w;
            regp = __logf(sqrtf(n2) + 1.f) * (0.001f / 33.f);
        }
        float v = wave_sum(part + disp + regp);
        if ((t & 63) == 0) red[t >> 6] = v;
        __syncthreads();
        if (t == 0) total += red[0] + red[1] + red[2] + red[3];
    }
    if (t == 0) out[0] = total * (1.f / BATCH);
}

extern "C" void kernel_launch(void* const* d_in, const int* in_sizes, int n_in,
                              void* d_out, int out_size, void* d_ws, size_t ws_size,
                              hipStream_t stream) {
    const float* emb   = (const float*)d_in[0];
    const int*   inst  = (const int*)  d_in[1];
    const float* kern  = (const float*)d_in[2];
    const float* tmask = (const float*)d_in[3];
    float* ws  = (float*)d_ws;
    float* out = (float*)d_out;

    const bool split    = ws_size >= NEED_SPLIT;
    const bool use_labs = ws_size >= NEED_LABS;
    unsigned* labs = use_labs ? (unsigned*)(ws + LABS_OFF_F) : nullptr;

    if (!split) init_aws<<<dim3((BATCH * 208 + 255) / 256), 256, 0, stream>>>(ws);
    dim3 grid(GXB, BATCH);
    if (split) pass1<true ><<<grid, 256, 0, stream>>>(emb, inst, kern, tmask, ws, labs);
    else       pass1<false><<<grid, 256, 0, stream>>>(emb, inst, kern, tmask, ws, labs);
    if (split) reduce_means<true ><<<BATCH, 256, 0, stream>>>(ws);
    else       reduce_means<false><<<BATCH, 256, 0, stream>>>(ws);
    if (use_labs) pass2<true ><<<grid, 256, 0, stream>>>(emb, inst, tmask, ws, labs);
    else          pass2<false><<<grid, 256, 0, stream>>>(emb, inst, tmask, ws, nullptr);
    final_kernel<<<1, 256, 0, stream>>>(ws, out);
}

// Round 8
// 167.036 us; speedup vs baseline: 1.0993x; 1.0993x over previous
//
#include <hip/hip_runtime.h>
#include <math.h>

#define HW    409600      // 640*640
#define HW4   102400      // quads per batch plane
#define BATCH 8
#define NLAB  33
#define CH    1024        // pixels per block chunk
#define NCH   (HW/CH)     // 400 blocks per batch
#define NREP  8           // LDS bin replicas (per 8-lane cluster)
#define RS    201         // replica stride (33*6=198 fields + pad)
// ws float-offset layout:
#define MEANS_OFF 0                        // [8][168]: mean[132], invci@132..164
#define P2_OFF    2048                     // [8][512] pass2 partials
#define AWS_OFF   6144                     // [8][208] atomic-fallback record
#define P1_OFF    8192                     // [3200][200] contiguous records
#define LABS_OFF_F (P1_OFF + BATCH*NCH*200)
#define NEED_SPLIT ((size_t)LABS_OFF_F * 4)
#define NEED_LABS  (NEED_SPLIT + (size_t)BATCH * HW4 * 4)

__global__ void init_aws(float* ws) {   // only for atomic-fallback mode
    int i = blockIdx.x * 256 + threadIdx.x;
    if (i < BATCH * 208) ws[AWS_OFF + i] = 0.f;
}

__device__ __forceinline__ float getc(const float4& v, int e) {
    return (e == 0) ? v.x : (e == 1) ? v.y : (e == 2) ? v.z : v.w;
}
__device__ __forceinline__ float wave_sum(float v) {
    #pragma unroll
    for (int o = 32; o > 0; o >>= 1) v += __shfl_xor(v, o);
    return v;
}

// async global->LDS: 16B per lane, wave-uniform LDS base + lane*16
__device__ __forceinline__ void stage16(const unsigned* g, float* l, int lane) {
#if defined(__has_builtin) && __has_builtin(__builtin_amdgcn_global_load_lds)
    __builtin_amdgcn_global_load_lds(
        (const __attribute__((address_space(1))) unsigned int*)(g + 4 * lane),
        (__attribute__((address_space(3))) unsigned int*)l, 16, 0, 0);
#else
    ((uint4*)l)[lane] = ((const uint4*)g)[lane];
#endif
}

__device__ __forceinline__ void acc1(int l, bool k,
                                     float x0, float x1, float x2, float x3,
                                     float* mb) {
    if (l) {
        float* bb = mb + l * 6;
        atomicAdd(bb + 5, 1.f);          // cnt_i
        if (k) {
            atomicAdd(bb + 0, x0);
            atomicAdd(bb + 1, x1);
            atomicAdd(bb + 2, x2);
            atomicAdd(bb + 3, x3);
            atomicAdd(bb + 4, 1.f);      // cnt_k
        }
    }
}

// ---------------- pass1: DMA-staged chunk -> LDS bins -> record ----------------
template<bool SPLIT>
__global__ __launch_bounds__(256, 4) void pass1(const float* __restrict__ emb,
                                                const int*   __restrict__ inst,
                                                const float* __restrict__ kern,
                                                const float* __restrict__ tmask,
                                                float*       __restrict__ ws,
                                                unsigned*    __restrict__ labs) {
    __shared__ float stage[7 * CH];      // 28 KB: inst,tm,kern,emb0..3
    __shared__ float bins[NREP][RS];     // 6.4 KB
    const int t = threadIdx.x, bx = blockIdx.x, b = blockIdx.y;
    const int wave = t >> 6, lane = t & 63;

    const size_t pixb = (size_t)bx * CH;
    const unsigned* gs[7];
    gs[0] = (const unsigned*)(inst  + (size_t)b * HW + pixb);
    gs[1] = (const unsigned*)(tmask + (size_t)b * HW + pixb);
    gs[2] = (const unsigned*)(kern  + (size_t)b * HW + pixb);
    #pragma unroll
    for (int d = 0; d < 4; ++d)
        gs[3 + d] = (const unsigned*)(emb + ((size_t)b * 4 + d) * HW + pixb);

    // 28 DMA wave-loads per block, 7 per wave, all in flight at once
    #pragma unroll
    for (int i = 0; i < 7; ++i) {
        int tau = wave * 7 + i;
        int s = tau >> 2, p = tau & 3;   // stream, 1KB part
        stage16(gs[s] + p * 256, &stage[s * CH + p * 256], lane);
    }

    float* mb = bins[(t >> 3) & (NREP - 1)];
    for (int i = t; i < NREP * RS; i += 256) (&bins[0][0])[i] = 0.f;
    __syncthreads();                     // drains vmcnt (DMA) + lgkm

    const int4*   sI = (const int4*)  (stage + 0 * CH);
    const float4* sT = (const float4*)(stage + 1 * CH);
    const float4* sK = (const float4*)(stage + 2 * CH);
    const float4* s0 = (const float4*)(stage + 3 * CH);
    const float4* s1 = (const float4*)(stage + 4 * CH);
    const float4* s2 = (const float4*)(stage + 5 * CH);
    const float4* s3 = (const float4*)(stage + 6 * CH);

    int4   iv = sI[t];
    float4 tv = sT[t];
    float4 kv = sK[t];
    float4 x0 = s0[t], x1 = s1[t], x2 = s2[t], x3 = s3[t];

    int l0 = (tv.x > 0.5f) ? iv.x : 0;
    int l1 = (tv.y > 0.5f) ? iv.y : 0;
    int l2 = (tv.z > 0.5f) ? iv.z : 0;
    int l3 = (tv.w > 0.5f) ? iv.w : 0;
    if (labs)
        labs[(size_t)b * HW4 + (size_t)bx * (CH / 4) + t] =
            (unsigned)l0 | ((unsigned)l1 << 8) |
            ((unsigned)l2 << 16) | ((unsigned)l3 << 24);

    acc1(l0, kv.x > 0.5f, x0.x, x1.x, x2.x, x3.x, mb);
    acc1(l1, kv.y > 0.5f, x0.y, x1.y, x2.y, x3.y, mb);
    acc1(l2, kv.z > 0.5f, x0.z, x1.z, x2.z, x3.z, mb);
    acc1(l3, kv.w > 0.5f, x0.w, x1.w, x2.w, x3.w, mb);
    __syncthreads();

    if (t < 198) {
        float v = 0.f;
        #pragma unroll
        for (int r = 0; r < NREP; ++r) v += bins[r][t];
        if (SPLIT)
            ws[P1_OFF + ((size_t)b * NCH + bx) * 200 + t] = v;  // contiguous record
        else if (v != 0.f)
            atomicAdd(ws + AWS_OFF + b * 208 + t, v);
    }
}

// ---------------- reduce: records -> means/invci ----------------
template<bool SPLIT>
__global__ __launch_bounds__(256) void reduce_means(float* __restrict__ ws) {
    __shared__ float raw[200];
    const int t = threadIdx.x, b = blockIdx.x;
    if (t < 198) {
        float s = 0.f;
        if (SPLIT) {
            const float* p = ws + P1_OFF + (size_t)b * NCH * 200 + t;
            float a0 = 0, a1 = 0, a2 = 0, a3 = 0, a4 = 0, a5 = 0, a6 = 0, a7 = 0;
            for (int i = 0; i < NCH; i += 8) {
                a0 += p[(i + 0) * 200]; a1 += p[(i + 1) * 200];
                a2 += p[(i + 2) * 200]; a3 += p[(i + 3) * 200];
                a4 += p[(i + 4) * 200]; a5 += p[(i + 5) * 200];
                a6 += p[(i + 6) * 200]; a7 += p[(i + 7) * 200];
            }
            s = ((a0 + a1) + (a2 + a3)) + ((a4 + a5) + (a6 + a7));
        } else {
            s = ws[AWS_OFF + b * 208 + t];
        }
        raw[t] = s;
    }
    __syncthreads();
    float* mm = ws + MEANS_OFF + b * 168;
    if (t < NLAB) {
        float ck = raw[t * 6 + 4], ci = raw[t * 6 + 5];
        float inv = 1.f / fmaxf(ck, 1.f);
        float z = (t == 0) ? 0.f : 1.f;
        mm[t * 4 + 0] = z * raw[t * 6 + 0] * inv;
        mm[t * 4 + 1] = z * raw[t * 6 + 1] * inv;
        mm[t * 4 + 2] = z * raw[t * 6 + 2] * inv;
        mm[t * 4 + 3] = z * raw[t * 6 + 3] * inv;
        mm[132 + t]   = 1.f / fmaxf(ci, 1.f);
    }
}

// ---------------- pass2: DMA-staged emb+labs -> val partial ----------------
template<bool USE_LABS>
__global__ __launch_bounds__(256, 6) void pass2(const float* __restrict__ emb,
                                                const int*   __restrict__ inst,
                                                const float* __restrict__ tmask,
                                                float*       __restrict__ ws,
                                                const unsigned* __restrict__ labs) {
    __shared__ float  stage[4 * CH + CH / 4];  // 17 KB: emb0..3 + labs
    __shared__ float4 means4[NLAB];
    __shared__ float  invci[NLAB];
    __shared__ float  red[4];
    const int t = threadIdx.x, bx = blockIdx.x, b = blockIdx.y;
    const int wave = t >> 6, lane = t & 63;
    const size_t pixb = (size_t)bx * CH;

    unsigned pk = 0;
    float4 x0, x1, x2, x3;
    if (USE_LABS) {
        const unsigned* gp[5];
        #pragma unroll
        for (int d = 0; d < 4; ++d)
            gp[d] = (const unsigned*)(emb + ((size_t)b * 4 + d) * HW + pixb);
        gp[4] = labs + (size_t)b * HW4 + (size_t)bx * (CH / 4);
        for (int tau = wave; tau < 17; tau += 4) {
            if (tau < 16) {
                int s = tau >> 2, p = tau & 3;
                stage16(gp[s] + p * 256, &stage[s * CH + p * 256], lane);
            } else {
                stage16(gp[4], &stage[4 * CH], lane);
            }
        }
    } else {
        const float4* emb4  = (const float4*)(emb + (size_t)b * 4 * HW);
        const int4*   inst4 = (const int4*)(inst + (size_t)b * HW);
        const float4* tm4   = (const float4*)(tmask + (size_t)b * HW);
        const int gq = bx * (CH / 4) + t;
        int4 iv = inst4[gq]; float4 tv = tm4[gq];
        pk = (unsigned)((tv.x > 0.5f) ? iv.x : 0)        |
             ((unsigned)((tv.y > 0.5f) ? iv.y : 0) << 8) |
             ((unsigned)((tv.z > 0.5f) ? iv.z : 0) << 16)|
             ((unsigned)((tv.w > 0.5f) ? iv.w : 0) << 24);
        x0 = emb4[gq]; x1 = emb4[gq + HW4];
        x2 = emb4[gq + 2 * HW4]; x3 = emb4[gq + 3 * HW4];
    }

    const float* mm = ws + MEANS_OFF + b * 168;
    if (t < NLAB) {
        means4[t] = ((const float4*)mm)[t];
        invci[t]  = mm[132 + t];
    }
    __syncthreads();

    if (USE_LABS) {
        pk = ((const unsigned*)(stage + 4 * CH))[t];
        x0 = ((const float4*)(stage + 0 * CH))[t];
        x1 = ((const float4*)(stage + 1 * CH))[t];
        x2 = ((const float4*)(stage + 2 * CH))[t];
        x3 = ((const float4*)(stage + 3 * CH))[t];
    }

    float acc = 0.f;
    #pragma unroll
    for (int e = 0; e < 4; ++e) {
        int l = (pk >> (8 * e)) & 255;
        if (l) {
            float4 m = means4[l];
            float d0 = getc(x0, e) - m.x, d1 = getc(x1, e) - m.y;
            float d2 = getc(x2, e) - m.z, d3 = getc(x3, e) - m.w;
            float dist = sqrtf(d0 * d0 + d1 * d1 + d2 * d2 + d3 * d3);
            float u = fmaxf(dist - 0.5f, 0.f);
            acc += __logf(u * u + 1.f) * invci[l];
        }
    }

    acc = wave_sum(acc);
    if ((t & 63) == 0) red[t >> 6] = acc;
    __syncthreads();
    if (t == 0)
        ws[P2_OFF + b * 512 + bx] = red[0] + red[1] + red[2] + red[3];
}

// ---------------- final: single block, all batches, plain store ----------------
__global__ __launch_bounds__(256) void final_kernel(const float* __restrict__ ws,
                                                    float* __restrict__ out) {
    __shared__ float4 means4[NLAB];
    __shared__ float  red[4];
    const int t = threadIdx.x;
    float total = 0.f;
    for (int b = 0; b < BATCH; ++b) {
        __syncthreads();
        const float* mm = ws + MEANS_OFF + b * 168;
        if (t < NLAB) means4[t] = ((const float4*)mm)[t];
        __syncthreads();

        float pa = 0.f;
        for (int i = t; i < NCH; i += 256) pa += ws[P2_OFF + b * 512 + i];
        pa *= (1.f / 32.f);                                   // l_agg
        float disp = 0.f;
        for (int p = t; p < 1024; p += 256) {
            int i = p >> 5, j = p & 31;
            if (i != j) {
                float4 mi = means4[i + 1], mj = means4[j + 1];
                float d0 = mi.x - mj.x, d1 = mi.y - mj.y;
                float d2 = mi.z - mj.z, d3 = mi.w - mj.w;
                float pd = sqrtf(d0 * d0 + d1 * d1 + d2 * d2 + d3 * d3);
                float u = fmaxf(3.0f - pd, 0.f);
                disp += __logf(u * u + 1.f);
            }
        }
        disp *= 1.f / 992.f;                                  // 32*31
        float regp = 0.f;
        if (t >= 1 && t < NLAB) {
            float4 m = means4[t];
            float n2 = m.x * m.x + m.y * m.y + m.z * m.z + m.w * m.w;
            regp = __logf(sqrtf(n2) + 1.f) * (0.001f / 33.f);
        }
        float v = wave_sum(pa + disp + regp);
        if ((t & 63) == 0) red[t >> 6] = v;
        __syncthreads();
        if (t == 0) total += red[0] + red[1] + red[2] + red[3];
    }
    if (t == 0) out[0] = total * (1.f / BATCH);
}

extern "C" void kernel_launch(void* const* d_in, const int* in_sizes, int n_in,
                              void* d_out, int out_size, void* d_ws, size_t ws_size,
                              hipStream_t stream) {
    const float* emb   = (const float*)d_in[0];
    const int*   inst  = (const int*)  d_in[1];
    const float* kern  = (const float*)d_in[2];
    const float* tmask = (const float*)d_in[3];
    float* ws  = (float*)d_ws;
    float* out = (float*)d_out;

    const bool split    = ws_size >= NEED_SPLIT;
    const bool use_labs = ws_size >= NEED_LABS;
    unsigned* labs = use_labs ? (unsigned*)(ws + LABS_OFF_F) : nullptr;

    if (!split) init_aws<<<dim3((BATCH * 208 + 255) / 256), 256, 0, stream>>>(ws);
    dim3 grid(NCH, BATCH);
    if (split) pass1<true ><<<grid, 256, 0, stream>>>(emb, inst, kern, tmask, ws, labs);
    else       pass1<false><<<grid, 256, 0, stream>>>(emb, inst, kern, tmask, ws, labs);
    if (split) reduce_means<true ><<<BATCH, 256, 0, stream>>>(ws);
    else       reduce_means<false><<<BATCH, 256, 0, stream>>>(ws);
    if (use_labs) pass2<true ><<<grid, 256, 0, stream>>>(emb, inst, tmask, ws, labs);
    else          pass2<false><<<grid, 256, 0, stream>>>(emb, inst, tmask, ws, nullptr);
    final_kernel<<<1, 256, 0, stream>>>(ws, out);
}

// Round 9
// 166.843 us; speedup vs baseline: 1.1005x; 1.0012x over previous
//
#include <hip/hip_runtime.h>
#include <math.h>

#define HW    409600      // 640*640
#define HW4   102400      // quads per batch plane
#define BATCH 8
#define NLAB  33
#define CH    1024        // pixels per block chunk
#define NCH   (HW/CH)     // 400 blocks per batch
#define NREP  4           // LDS bin replicas (per 16-lane cluster)
#define RS    201         // replica stride (33*6=198 fields + pad)
// ws float-offset layout:
#define MEANS_OFF 0                        // [8][168]: mean[132], invci@132..164
#define P2_OFF    2048                     // [8][512] pass2 partials
#define AWS_OFF   6144                     // [8][208] atomic-fallback record
#define P1_OFF    8192                     // [3200][200] contiguous records
#define LABS_OFF_F (P1_OFF + BATCH*NCH*200)
#define NEED_SPLIT ((size_t)LABS_OFF_F * 4)
#define NEED_LABS  (NEED_SPLIT + (size_t)BATCH * HW4 * 4)

__global__ void init_aws(float* ws) {   // only for atomic-fallback mode
    int i = blockIdx.x * 256 + threadIdx.x;
    if (i < BATCH * 208) ws[AWS_OFF + i] = 0.f;
}

__device__ __forceinline__ float getc(const float4& v, int e) {
    return (e == 0) ? v.x : (e == 1) ? v.y : (e == 2) ? v.z : v.w;
}
__device__ __forceinline__ float wave_sum(float v) {
    #pragma unroll
    for (int o = 32; o > 0; o >>= 1) v += __shfl_xor(v, o);
    return v;
}

// async global->LDS: 16B per lane, wave-uniform LDS base + lane*16
__device__ __forceinline__ void stage16(const unsigned* g, float* l, int lane) {
#if defined(__has_builtin) && __has_builtin(__builtin_amdgcn_global_load_lds)
    __builtin_amdgcn_global_load_lds(
        (const __attribute__((address_space(1))) unsigned int*)(g + 4 * lane),
        (__attribute__((address_space(3))) unsigned int*)l, 16, 0, 0);
#else
    ((uint4*)l)[lane] = ((const uint4*)g)[lane];
#endif
}

__device__ __forceinline__ void acc1(int l, bool k,
                                     float x0, float x1, float x2, float x3,
                                     float* mb) {
    if (l) {
        float* bb = mb + l * 6;
        atomicAdd(bb + 5, 1.f);          // cnt_i
        if (k) {
            atomicAdd(bb + 0, x0);
            atomicAdd(bb + 1, x1);
            atomicAdd(bb + 2, x2);
            atomicAdd(bb + 3, x3);
            atomicAdd(bb + 4, 1.f);      // cnt_k
        }
    }
}

// ---------------- pass1: DMA-staged chunk -> LDS bins -> record ----------------
template<bool SPLIT>
__global__ __launch_bounds__(256, 5) void pass1(const float* __restrict__ emb,
                                                const int*   __restrict__ inst,
                                                const float* __restrict__ kern,
                                                const float* __restrict__ tmask,
                                                float*       __restrict__ ws,
                                                unsigned*    __restrict__ labs) {
    __shared__ float stage[7 * CH];      // 28 KB: inst,tm,kern,emb0..3
    __shared__ float bins[NREP][RS];     // 3.2 KB
    const int t = threadIdx.x, bx = blockIdx.x, b = blockIdx.y;
    const int wave = t >> 6, lane = t & 63;

    const size_t pixb = (size_t)bx * CH;
    const unsigned* gs[7];
    gs[0] = (const unsigned*)(inst  + (size_t)b * HW + pixb);
    gs[1] = (const unsigned*)(tmask + (size_t)b * HW + pixb);
    gs[2] = (const unsigned*)(kern  + (size_t)b * HW + pixb);
    #pragma unroll
    for (int d = 0; d < 4; ++d)
        gs[3 + d] = (const unsigned*)(emb + ((size_t)b * 4 + d) * HW + pixb);

    // 28 DMA wave-loads per block, 7 per wave, all in flight at once
    #pragma unroll
    for (int i = 0; i < 7; ++i) {
        int tau = wave * 7 + i;
        int s = tau >> 2, p = tau & 3;   // stream, 1KB part
        stage16(gs[s] + p * 256, &stage[s * CH + p * 256], lane);
    }

    float* mb = bins[(t >> 4) & (NREP - 1)];
    for (int i = t; i < NREP * RS; i += 256) (&bins[0][0])[i] = 0.f;
    __syncthreads();                     // drains vmcnt (DMA) + lgkm

    const int4*   sI = (const int4*)  (stage + 0 * CH);
    const float4* sT = (const float4*)(stage + 1 * CH);
    const float4* sK = (const float4*)(stage + 2 * CH);
    const float4* s0 = (const float4*)(stage + 3 * CH);
    const float4* s1 = (const float4*)(stage + 4 * CH);
    const float4* s2 = (const float4*)(stage + 5 * CH);
    const float4* s3 = (const float4*)(stage + 6 * CH);

    int4   iv = sI[t];
    float4 tv = sT[t];
    float4 kv = sK[t];
    float4 x0 = s0[t], x1 = s1[t], x2 = s2[t], x3 = s3[t];

    int l0 = (tv.x > 0.5f) ? iv.x : 0;
    int l1 = (tv.y > 0.5f) ? iv.y : 0;
    int l2 = (tv.z > 0.5f) ? iv.z : 0;
    int l3 = (tv.w > 0.5f) ? iv.w : 0;
    if (labs)
        labs[(size_t)b * HW4 + (size_t)bx * (CH / 4) + t] =
            (unsigned)l0 | ((unsigned)l1 << 8) |
            ((unsigned)l2 << 16) | ((unsigned)l3 << 24);

    acc1(l0, kv.x > 0.5f, x0.x, x1.x, x2.x, x3.x, mb);
    acc1(l1, kv.y > 0.5f, x0.y, x1.y, x2.y, x3.y, mb);
    acc1(l2, kv.z > 0.5f, x0.z, x1.z, x2.z, x3.z, mb);
    acc1(l3, kv.w > 0.5f, x0.w, x1.w, x2.w, x3.w, mb);
    __syncthreads();

    if (t < 198) {
        float v = 0.f;
        #pragma unroll
        for (int r = 0; r < NREP; ++r) v += bins[r][t];
        if (SPLIT)
            ws[P1_OFF + ((size_t)b * NCH + bx) * 200 + t] = v;  // contiguous record
        else if (v != 0.f)
            atomicAdd(ws + AWS_OFF + b * 208 + t, v);
    }
}

// ---------------- reduce: records -> means/invci ----------------
template<bool SPLIT>
__global__ __launch_bounds__(256) void reduce_means(float* __restrict__ ws) {
    __shared__ float raw[200];
    const int t = threadIdx.x, b = blockIdx.x;
    if (t < 198) {
        float s = 0.f;
        if (SPLIT) {
            const float* p = ws + P1_OFF + (size_t)b * NCH * 200 + t;
            float a0 = 0, a1 = 0, a2 = 0, a3 = 0, a4 = 0, a5 = 0, a6 = 0, a7 = 0;
            for (int i = 0; i < NCH; i += 8) {
                a0 += p[(i + 0) * 200]; a1 += p[(i + 1) * 200];
                a2 += p[(i + 2) * 200]; a3 += p[(i + 3) * 200];
                a4 += p[(i + 4) * 200]; a5 += p[(i + 5) * 200];
                a6 += p[(i + 6) * 200]; a7 += p[(i + 7) * 200];
            }
            s = ((a0 + a1) + (a2 + a3)) + ((a4 + a5) + (a6 + a7));
        } else {
            s = ws[AWS_OFF + b * 208 + t];
        }
        raw[t] = s;
    }
    __syncthreads();
    float* mm = ws + MEANS_OFF + b * 168;
    if (t < NLAB) {
        float ck = raw[t * 6 + 4], ci = raw[t * 6 + 5];
        float inv = 1.f / fmaxf(ck, 1.f);
        float z = (t == 0) ? 0.f : 1.f;
        mm[t * 4 + 0] = z * raw[t * 6 + 0] * inv;
        mm[t * 4 + 1] = z * raw[t * 6 + 1] * inv;
        mm[t * 4 + 2] = z * raw[t * 6 + 2] * inv;
        mm[t * 4 + 3] = z * raw[t * 6 + 3] * inv;
        mm[132 + t]   = 1.f / fmaxf(ci, 1.f);
    }
}

// ---------------- pass2: DMA-staged emb+labs -> val partial ----------------
template<bool USE_LABS>
__global__ __launch_bounds__(256, 7) void pass2(const float* __restrict__ emb,
                                                const int*   __restrict__ inst,
                                                const float* __restrict__ tmask,
                                                float*       __restrict__ ws,
                                                const unsigned* __restrict__ labs) {
    __shared__ float  stage[4 * CH + CH / 4];  // 17 KB: emb0..3 + labs
    __shared__ float4 means4[NLAB];
    __shared__ float  invci[NLAB];
    __shared__ float  red[4];
    const int t = threadIdx.x, bx = blockIdx.x, b = blockIdx.y;
    const int wave = t >> 6, lane = t & 63;
    const size_t pixb = (size_t)bx * CH;

    unsigned pk = 0;
    float4 x0, x1, x2, x3;
    if (USE_LABS) {
        const unsigned* gp[5];
        #pragma unroll
        for (int d = 0; d < 4; ++d)
            gp[d] = (const unsigned*)(emb + ((size_t)b * 4 + d) * HW + pixb);
        gp[4] = labs + (size_t)b * HW4 + (size_t)bx * (CH / 4);
        for (int tau = wave; tau < 17; tau += 4) {
            if (tau < 16) {
                int s = tau >> 2, p = tau & 3;
                stage16(gp[s] + p * 256, &stage[s * CH + p * 256], lane);
            } else {
                stage16(gp[4], &stage[4 * CH], lane);
            }
        }
    } else {
        const float4* emb4  = (const float4*)(emb + (size_t)b * 4 * HW);
        const int4*   inst4 = (const int4*)(inst + (size_t)b * HW);
        const float4* tm4   = (const float4*)(tmask + (size_t)b * HW);
        const int gq = bx * (CH / 4) + t;
        int4 iv = inst4[gq]; float4 tv = tm4[gq];
        pk = (unsigned)((tv.x > 0.5f) ? iv.x : 0)        |
             ((unsigned)((tv.y > 0.5f) ? iv.y : 0) << 8) |
             ((unsigned)((tv.z > 0.5f) ? iv.z : 0) << 16)|
             ((unsigned)((tv.w > 0.5f) ? iv.w : 0) << 24);
        x0 = emb4[gq]; x1 = emb4[gq + HW4];
        x2 = emb4[gq + 2 * HW4]; x3 = emb4[gq + 3 * HW4];
    }

    const float* mm = ws + MEANS_OFF + b * 168;
    if (t < NLAB) {
        means4[t] = ((const float4*)mm)[t];
        invci[t]  = mm[132 + t];
    }
    __syncthreads();

    if (USE_LABS) {
        pk = ((const unsigned*)(stage + 4 * CH))[t];
        x0 = ((const float4*)(stage + 0 * CH))[t];
        x1 = ((const float4*)(stage + 1 * CH))[t];
        x2 = ((const float4*)(stage + 2 * CH))[t];
        x3 = ((const float4*)(stage + 3 * CH))[t];
    }

    float acc = 0.f;
    #pragma unroll
    for (int e = 0; e < 4; ++e) {
        int l = (pk >> (8 * e)) & 255;
        if (l) {
            float4 m = means4[l];
            float d0 = getc(x0, e) - m.x, d1 = getc(x1, e) - m.y;
            float d2 = getc(x2, e) - m.z, d3 = getc(x3, e) - m.w;
            float dist = sqrtf(d0 * d0 + d1 * d1 + d2 * d2 + d3 * d3);
            float u = fmaxf(dist - 0.5f, 0.f);
            acc += __logf(u * u + 1.f) * invci[l];
        }
    }

    acc = wave_sum(acc);
    if ((t & 63) == 0) red[t >> 6] = acc;
    __syncthreads();
    if (t == 0)
        ws[P2_OFF + b * 512 + bx] = red[0] + red[1] + red[2] + red[3];
}

// ---------------- final: single block, all batches, plain store ----------------
__global__ __launch_bounds__(256) void final_kernel(const float* __restrict__ ws,
                                                    float* __restrict__ out) {
    __shared__ float4 means4[NLAB];
    __shared__ float  red[4];
    const int t = threadIdx.x;
    float total = 0.f;
    for (int b = 0; b < BATCH; ++b) {
        __syncthreads();
        const float* mm = ws + MEANS_OFF + b * 168;
        if (t < NLAB) means4[t] = ((const float4*)mm)[t];
        __syncthreads();

        float pa = 0.f;
        for (int i = t; i < NCH; i += 256) pa += ws[P2_OFF + b * 512 + i];
        pa *= (1.f / 32.f);                                   // l_agg
        float disp = 0.f;
        for (int p = t; p < 1024; p += 256) {
            int i = p >> 5, j = p & 31;
            if (i != j) {
                float4 mi = means4[i + 1], mj = means4[j + 1];
                float d0 = mi.x - mj.x, d1 = mi.y - mj.y;
                float d2 = mi.z - mj.z, d3 = mi.w - mj.w;
                float pd = sqrtf(d0 * d0 + d1 * d1 + d2 * d2 + d3 * d3);
                float u = fmaxf(3.0f - pd, 0.f);
                disp += __logf(u * u + 1.f);
            }
        }
        disp *= 1.f / 992.f;                                  // 32*31
        float regp = 0.f;
        if (t >= 1 && t < NLAB) {
            float4 m = means4[t];
            float n2 = m.x * m.x + m.y * m.y + m.z * m.z + m.w * m.w;
            regp = __logf(sqrtf(n2) + 1.f) * (0.001f / 33.f);
        }
        float v = wave_sum(pa + disp + regp);
        if ((t & 63) == 0) red[t >> 6] = v;
        __syncthreads();
        if (t == 0) total += red[0] + red[1] + red[2] + red[3];
    }
    if (t == 0) out[0] = total * (1.f / BATCH);
}

extern "C" void kernel_launch(void* const* d_in, const int* in_sizes, int n_in,
                              void* d_out, int out_size, void* d_ws, size_t ws_size,
                              hipStream_t stream) {
    const float* emb   = (const float*)d_in[0];
    const int*   inst  = (const int*)  d_in[1];
    const float* kern  = (const float*)d_in[2];
    const float* tmask = (const float*)d_in[3];
    float* ws  = (float*)d_ws;
    float* out = (float*)d_out;

    const bool split    = ws_size >= NEED_SPLIT;
    const bool use_labs = ws_size >= NEED_LABS;
    unsigned* labs = use_labs ? (unsigned*)(ws + LABS_OFF_F) : nullptr;

    if (!split) init_aws<<<dim3((BATCH * 208 + 255) / 256), 256, 0, stream>>>(ws);
    dim3 grid(NCH, BATCH);
    if (split) pass1<true ><<<grid, 256, 0, stream>>>(emb, inst, kern, tmask, ws, labs);
    else       pass1<false><<<grid, 256, 0, stream>>>(emb, inst, kern, tmask, ws, labs);
    if (split) reduce_means<true ><<<BATCH, 256, 0, stream>>>(ws);
    else       reduce_means<false><<<BATCH, 256, 0, stream>>>(ws);
    if (use_labs) pass2<true ><<<grid, 256, 0, stream>>>(emb, inst, tmask, ws, labs);
    else          pass2<false><<<grid, 256, 0, stream>>>(emb, inst, tmask, ws, nullptr);
    final_kernel<<<1, 256, 0, stream>>>(ws, out);
}